// Round 5
// baseline (203.856 us; speedup 1.0000x reference)
//
#include <hip/hip_runtime.h>
#include <math.h>

#define PCAP 512  // per-block LDS positive-pair staging capacity

typedef _Float16 half8 __attribute__((ext_vector_type(8)));
typedef _Float16 half2v __attribute__((ext_vector_type(2)));
typedef float f32x4 __attribute__((ext_vector_type(4)));

// ---------------------------------------------------------------------------
// Kernel 1: row normalization (4 rows per block, one per wave) + workspace
// zeroing fused in (removes a memset dispatch).
__global__ __launch_bounds__(256) void norm_kernel(
    const float* __restrict__ X, _Float16* __restrict__ Yh,
    float* __restrict__ unsim, float* __restrict__ accum, float inv_sqrtT) {
  int t = threadIdx.x;
  int w = t >> 6, lane = t & 63;
  int row = blockIdx.x * 4 + w;
  float2 v = ((const float2*)(X + (size_t)row * 128))[lane];
  float s = v.x * v.x + v.y * v.y;
#pragma unroll
  for (int m = 1; m < 64; m <<= 1) s += __shfl_xor(s, m);
  float inv = inv_sqrtT * rsqrtf(fmaxf(s, 1e-24f));
  half2v h;
  h.x = (_Float16)(v.x * inv);
  h.y = (_Float16)(v.y * inv);
  ((half2v*)(Yh + (size_t)row * 128))[lane] = h;
  // zero 4 unsim entries per block; block 0 zeroes accum[0..3] + pcur slot
  if (t < 4) unsim[blockIdx.x * 4 + t] = 0.f;
  if (blockIdx.x == 0 && t < 8) accum[t] = 0.f;  // accum[0..5]+pcur(6..7)
}

// ---------------------------------------------------------------------------
// Kernel 2: MFMA similarity pass over upper-triangular 64x64 tile pairs.
// 4 waves per block, each a 32x32 quadrant (2x2x4 grid of 16x16x32 f16 MFMA).
// LDS ~39 KB -> 4 blocks/CU. Epilogue: exp + label mask; row/col sums go
// STRAIGHT to global unsim via fire-and-forget atomics (no LDS reduce
// stage, no extra barriers). Positives appended to small LDS buffer.
__global__ __launch_bounds__(256, 4) void pass1_kernel(
    const _Float16* __restrict__ Yh, const int* __restrict__ lab,
    float* __restrict__ unsim, uint2* __restrict__ posBuf,
    int* __restrict__ pcur, int nt) {
  __shared__ _Float16 As[64][136];  // +8 halves pad: 2-way conflicts (free)
  __shared__ _Float16 Bs[64][136];
  __shared__ int labR[64], labC[64];
  __shared__ uint2 posS[PCAP];
  __shared__ int posCnt, gbaseS;

  // decode linear block id -> (bi, bj), bi <= bj (triangular)
  int b = blockIdx.x;
  float ntf = (float)nt;
  int bi = (int)((2.f * ntf + 1.f -
                  sqrtf((2.f * ntf + 1.f) * (2.f * ntf + 1.f) - 8.f * (float)b)) *
                 0.5f);
  if (bi < 0) bi = 0;
  while ((bi + 1) * nt - ((bi + 1) * bi) / 2 <= b) ++bi;
  while (bi * nt - (bi * (bi - 1)) / 2 > b) --bi;
  int bj = bi + (b - (bi * nt - (bi * (bi - 1)) / 2));
  const int i0 = bi * 64, j0 = bj * 64;
  const bool offdiag = (bi != bj);

  const int t = threadIdx.x;
  const float4* Yg = (const float4*)Yh;
  // stage A and B tiles: 64 rows x 16 float4-chunks each
#pragma unroll
  for (int c = t; c < 1024; c += 256) {
    int row = c >> 4, kc = c & 15;
    *(float4*)&As[row][kc * 8] = Yg[(size_t)(i0 + row) * 16 + kc];
    *(float4*)&Bs[row][kc * 8] = Yg[(size_t)(j0 + row) * 16 + kc];
  }
  if (t < 64) labR[t] = lab[i0 + t];
  else if (t < 128) labC[t - 64] = lab[j0 + t - 64];
  if (t == 0) posCnt = 0;
  __syncthreads();

  const int w = t >> 6, lane = t & 63;
  const int quad = lane >> 4, l16 = lane & 15;
  const int rbase = (w >> 1) * 32, cbase = (w & 1) * 32;

  f32x4 acc[2][2] = {};
#pragma unroll
  for (int ks = 0; ks < 4; ++ks) {
    const int kof = ks * 32 + quad * 8;
    half8 af[2], bf[2];
#pragma unroll
    for (int p = 0; p < 2; ++p)
      af[p] = *(const half8*)&As[rbase + p * 16 + l16][kof];
#pragma unroll
    for (int p = 0; p < 2; ++p)
      bf[p] = *(const half8*)&Bs[cbase + p * 16 + l16][kof];
#pragma unroll
    for (int pi = 0; pi < 2; ++pi)
#pragma unroll
      for (int pj = 0; pj < 2; ++pj)
        acc[pi][pj] = __builtin_amdgcn_mfma_f32_16x16x32_f16(
            af[pi], bf[pj], acc[pi][pj], 0, 0, 0);
  }

  // ---- epilogue ----
  int lr[2][4], lc[2];
#pragma unroll
  for (int pi = 0; pi < 2; ++pi)
#pragma unroll
    for (int r = 0; r < 4; ++r) lr[pi][r] = labR[rbase + pi * 16 + quad * 4 + r];
#pragma unroll
  for (int pj = 0; pj < 2; ++pj) lc[pj] = labC[cbase + pj * 16 + l16];

  float rowp[2][4] = {};
  float colp[2] = {0.f, 0.f};
#pragma unroll
  for (int pi = 0; pi < 2; ++pi)
#pragma unroll
    for (int pj = 0; pj < 2; ++pj)
#pragma unroll
      for (int r = 0; r < 4; ++r) {
        const bool same = (lr[pi][r] == lc[pj]);
        float s = acc[pi][pj][r];
        float e = same ? 0.f : __expf(s);
        rowp[pi][r] += e;
        colp[pj] += e;
        if (same) {  // rare (~1/128): per-lane divergent path
          const int gi = i0 + rbase + pi * 16 + quad * 4 + r;
          const int gj = j0 + cbase + pj * 16 + l16;
          if (offdiag || (gi != gj)) {
            int nadd = offdiag ? 2 : 1;
            int s0 = atomicAdd(&posCnt, nadd);
            unsigned sb = __float_as_uint(s);
            uint2 e0 = {(unsigned)gi, sb};
            if (s0 < PCAP) posS[s0] = e0;
            else posBuf[atomicAdd(pcur, 1)] = e0;
            if (offdiag) {
              uint2 e1 = {(unsigned)gj, sb};
              if (s0 + 1 < PCAP) posS[s0 + 1] = e1;
              else posBuf[atomicAdd(pcur, 1)] = e1;
            }
          }
        }
      }

  // row sums: reduce over the 16 cols this lane-group covers, then straight
  // to global (fire-and-forget atomics, no LDS staging)
#pragma unroll
  for (int pi = 0; pi < 2; ++pi)
#pragma unroll
    for (int r = 0; r < 4; ++r) {
      float v = rowp[pi][r];
      v += __shfl_xor(v, 1);
      v += __shfl_xor(v, 2);
      v += __shfl_xor(v, 4);
      v += __shfl_xor(v, 8);
      if (l16 == 0)
        atomicAdd(&unsim[i0 + rbase + pi * 16 + quad * 4 + r], v);
    }
  // col sums (mirror band): reduce across quads
  if (offdiag) {
#pragma unroll
    for (int pj = 0; pj < 2; ++pj) {
      float v = colp[pj];
      v += __shfl_xor(v, 16);
      v += __shfl_xor(v, 32);
      if (quad == 0) atomicAdd(&unsim[j0 + cbase + pj * 16 + l16], v);
    }
  }

  // flush positive records (LDS-staged part)
  __syncthreads();
  int total = posCnt < PCAP ? posCnt : PCAP;
  if (t == 0) gbaseS = atomicAdd(pcur, total);
  __syncthreads();
  for (int e = t; e < total; e += 256) posBuf[gbaseS + e] = posS[e];
}

// ---------------------------------------------------------------------------
// Kernel 3: stream positive records: term = log(exp(s) + unsim[idx]) - s,
// with finalize fused via last-block-done pattern (saves a dispatch).
__global__ __launch_bounds__(256) void pass3_kernel(
    const uint2* __restrict__ posBuf, int* __restrict__ pcur,
    const float* __restrict__ unsim, float* __restrict__ accum,
    float* __restrict__ out) {
  int n = *pcur;
  float local = 0.f;
  int stride = 256 * gridDim.x;
  for (int p = blockIdx.x * 256 + threadIdx.x; p < n; p += stride) {
    uint2 e = posBuf[p];
    float s = __uint_as_float(e.y);
    local += logf(__expf(s) + unsim[e.x]) - s;
  }
  __shared__ float red[4];
#pragma unroll
  for (int msk = 1; msk < 64; msk <<= 1) local += __shfl_xor(local, msk);
  int lane = threadIdx.x & 63, w = threadIdx.x >> 6;
  if (lane == 0) red[w] = local;
  __syncthreads();
  if (threadIdx.x == 0) {
    atomicAdd(&accum[0], red[0] + red[1] + red[2] + red[3]);
    __threadfence();
    int* done = (int*)&accum[2];
    if (atomicAdd(done, 1) == (int)gridDim.x - 1) {
      float ls = __hip_atomic_load(&accum[0], __ATOMIC_ACQUIRE,
                                   __HIP_MEMORY_SCOPE_AGENT);
      out[0] = ls / (float)n;
    }
  }
}

// ---------------------------------------------------------------------------
extern "C" void kernel_launch(void* const* d_in, const int* in_sizes, int n_in,
                              void* d_out, int out_size, void* d_ws,
                              size_t ws_size, hipStream_t stream) {
  const float* X = (const float*)d_in[0];
  const int* lab = (const int*)d_in[1];
  float* out = (float*)d_out;

  const int N = in_sizes[1];  // 8192; D fixed at 128

  // workspace layout
  _Float16* Yh = (_Float16*)d_ws;                 // N*128 f16 (2 MB)
  float* unsim = (float*)(Yh + (size_t)N * 128);  // N f32
  float* accum = unsim + N;                       // [0] loss, [2] done ctr
  int* pcur = (int*)(accum + 6);                  // record cursor (+ pad)
  uint2* posBuf = (uint2*)(pcur + 2);             // ~516k entries

  const float inv_sqrtT = 2.2360679775f;  // 1/sqrt(0.2)
  norm_kernel<<<N / 4, 256, 0, stream>>>(X, Yh, unsim, accum, inv_sqrtT);

  const int nt = N / 64;               // 128 tiles per dim
  const int nblk = nt * (nt + 1) / 2;  // 8256 upper-tri tile pairs
  pass1_kernel<<<nblk, 256, 0, stream>>>(Yh, lab, unsim, posBuf, pcur, nt);
  pass3_kernel<<<512, 256, 0, stream>>>(posBuf, pcur, unsim, accum, out);
}